// Round 1
// baseline (1290.761 us; speedup 1.0000x reference)
//
#include <hip/hip_runtime.h>

#define HID 30
#define TSTEPS 2048
#define BATCH 512
#define L2E 1.4426950408889634f

__device__ __forceinline__ float fexp2(float x) { return __builtin_amdgcn_exp2f(x); }
__device__ __forceinline__ float frcp(float x)  { return __builtin_amdgcn_rcpf(x); }
__device__ __forceinline__ void  pinf(float& v) { asm("" : "+v"(v)); }

// broadcast lane l of v to all lanes (v_readlane -> SGPR)
__device__ __forceinline__ float rl(float v, int l) {
    return __int_as_float(__builtin_amdgcn_readlane(__float_as_int(v), l));
}

// p from the other 32-lane half (lane ^ 32) via gfx950 VALU permlane32_swap.
__device__ __forceinline__ float other_half(float p, int h) {
#if __has_builtin(__builtin_amdgcn_permlane32_swap)
    auto r = __builtin_amdgcn_permlane32_swap(__float_as_uint(p), __float_as_uint(p),
                                              false, false);
    return __uint_as_float(h ? r[0] : r[1]);
#else
    return __shfl_xor(p, 32);
#endif
}

// Wave-wide sum via DPP (VALU pipe). Valid in lane 63.
__device__ __forceinline__ float dpp_reduce63(float x) {
    x += __int_as_float(__builtin_amdgcn_update_dpp(0, __float_as_int(x), 0x111, 0xf, 0xf, true));
    x += __int_as_float(__builtin_amdgcn_update_dpp(0, __float_as_int(x), 0x112, 0xf, 0xf, true));
    x += __int_as_float(__builtin_amdgcn_update_dpp(0, __float_as_int(x), 0x114, 0xf, 0xf, true));
    x += __int_as_float(__builtin_amdgcn_update_dpp(0, __float_as_int(x), 0x118, 0xf, 0xf, true));
    x += __int_as_float(__builtin_amdgcn_update_dpp(0, __float_as_int(x), 0x142, 0xf, 0xf, true));
    x += __int_as_float(__builtin_amdgcn_update_dpp(0, __float_as_int(x), 0x143, 0xf, 0xf, true));
    return x;
}

// ONE WAVE PER BATCH ELEMENT — no barriers, no LDS, both layers + fc in-wave.
// All weights live in VGPRs (6 x 30 = 180). h1/h2 broadcasts via readlane,
// consumed immediately; each h1 broadcast feeds BOTH W_hh1 (carried partial for
// step t+1) and W_ih2 (this step). Loop-carried chain ~150 cy << issue ~590 cy
// per step -> issue-bound on a private SIMD (2 waves/CU over 4 SIMDs).
__global__ __launch_bounds__(64, 1)
void lstm2_kernel(const float* __restrict__ x,
                  const float* __restrict__ w_ih1, const float* __restrict__ w_hh1,
                  const float* __restrict__ b_ih1, const float* __restrict__ b_hh1,
                  const float* __restrict__ w_ih2, const float* __restrict__ w_hh2,
                  const float* __restrict__ b_ih2, const float* __restrict__ b_hh2,
                  const float* __restrict__ w_fc,  const float* __restrict__ b_fc,
                  float* __restrict__ out)
{
    const int b    = blockIdx.x;
    const int lane = threadIdx.x & 63;
    const int k    = lane & 31;
    const int h    = lane >> 5;
    const int kk   = (k < HID) ? k : (HID - 1);  // lanes k=30,31 duplicate unit 29
    const int rowA = h * 30 + kk;                // h0: i-row, h1: f-row
    const int rowB = 60 + h * 30 + kk;           // h0: g-row, h1: o-row

    // ---- per-lane weights, all in registers ----
    float w1A[30], w1B[30];    // w_hh1 rows
    float wi2A[30], wi2B[30];  // w_ih2 rows
    float wh2A[30], wh2B[30];  // w_hh2 rows
#pragma unroll
    for (int j = 0; j < 30; ++j) {
        w1A[j]  = w_hh1[rowA * HID + j];
        w1B[j]  = w_hh1[rowB * HID + j];
        wi2A[j] = w_ih2[rowA * HID + j];
        wi2B[j] = w_ih2[rowB * HID + j];
        wh2A[j] = w_hh2[rowA * HID + j];
        wh2B[j] = w_hh2[rowB * HID + j];
    }
    const float b1A = b_ih1[rowA] + b_hh1[rowA];
    const float b1B = b_ih1[rowB] + b_hh1[rowB];
    const float b2A = b_ih2[rowA] + b_hh2[rowA];
    const float b2B = b_ih2[rowB] + b_hh2[rowB];
    float wxa = w_ih1[rowA];
    float wxb = w_ih1[rowB];
    float wfck = (h && k < HID) ? w_fc[k] : 0.0f;
#pragma unroll
    for (int j = 0; j < 30; ++j) {
        pinf(w1A[j]); pinf(w1B[j]); pinf(wi2A[j]); pinf(wi2B[j]);
        pinf(wh2A[j]); pinf(wh2B[j]);
    }
    pinf(wxa); pinf(wxb); pinf(wfck);
    const float bfc = __int_as_float(__builtin_amdgcn_readfirstlane(__float_as_int(b_fc[0])));

    // gate-y activation constants: h0 -> tanh (g), h1 -> sigmoid (o)
    const float cy = h ? (-L2E) : (-2.0f * L2E);
    const float my = h ? 1.0f : 2.0f;
    const float ay = h ? 0.0f : -1.0f;

    float c1 = 0.0f, c2 = 0.0f;

    // carried partial pre-activations:
    //   aA1*/aB1* = b1 + W_hh1 . h1(t-1)   (computed during step t-1)
    //   hA2*/hB2* =      W_hh2 . h2(t-1)
    float aA1e = b1A, aA1o = 0.0f, aB1e = b1B, aB1o = 0.0f;
    float hA2e = 0.0f, hA2o = 0.0f, hB2e = 0.0f, hB2o = 0.0f;

    const float* xp   = x   + (size_t)b * TSTEPS;
    float*       outp = out + (size_t)b * TSTEPS;

    // x double-buffer: xv_cur covers [t & ~63, +64), xv_nxt the next chunk
    float xv_cur = xp[lane];
    float xv_nxt = xp[64 + lane];

#pragma unroll 2
    for (int t = 0; t < TSTEPS; ++t) {
        // ---------------- layer 1, step t ----------------
        const float xt    = rl(xv_cur, t & 63);
        const float pre1A = fmaf(xt, wxa, aA1e + aA1o);
        const float pre1B = fmaf(xt, wxb, aB1e + aB1o);
        const float gx1 = frcp(1.0f + fexp2(pre1A * (-L2E)));           // i / f
        const float gy1 = fmaf(frcp(1.0f + fexp2(pre1B * cy)), my, ay); // g / o
        const float p1  = gx1 * gy1;
        const float px1 = other_half(p1, h);
        c1 = fmaf(gx1, c1, px1);                 // h=1: f*c1 + i*g
        const float tc1 = fmaf(2.0f, frcp(1.0f + fexp2(c1 * (-2.0f * L2E))), -1.0f);
        const float hh1 = gy1 * tc1;             // h1(t)[kk], valid in h=1 half

        // ---- broadcast h1(t) once; feed W_hh1 (for t+1) AND W_ih2 (for t) ----
        aA1e = b1A; aA1o = 0.0f; aB1e = b1B; aB1o = 0.0f;
        float iA2e = b2A, iA2o = 0.0f, iB2e = b2B, iB2o = 0.0f;
#pragma unroll
        for (int j = 0; j < 30; j += 2) {
            const float s0 = rl(hh1, 32 + j);
            const float s1 = rl(hh1, 33 + j);
            aA1e = fmaf(w1A[j],      s0, aA1e);
            aA1o = fmaf(w1A[j + 1],  s1, aA1o);
            aB1e = fmaf(w1B[j],      s0, aB1e);
            aB1o = fmaf(w1B[j + 1],  s1, aB1o);
            iA2e = fmaf(wi2A[j],     s0, iA2e);
            iA2o = fmaf(wi2A[j + 1], s1, iA2o);
            iB2e = fmaf(wi2B[j],     s0, iB2e);
            iB2o = fmaf(wi2B[j + 1], s1, iB2o);
        }

        // ---------------- layer 2, step t ----------------
        const float pre2A = (iA2e + iA2o) + (hA2e + hA2o);
        const float pre2B = (iB2e + iB2o) + (hB2e + hB2o);
        const float gx2 = frcp(1.0f + fexp2(pre2A * (-L2E)));
        const float gy2 = fmaf(frcp(1.0f + fexp2(pre2B * cy)), my, ay);
        const float p2  = gx2 * gy2;
        const float px2 = other_half(p2, h);
        c2 = fmaf(gx2, c2, px2);
        const float tc2 = fmaf(2.0f, frcp(1.0f + fexp2(c2 * (-2.0f * L2E))), -1.0f);
        const float hh2 = gy2 * tc2;             // h2(t)[kk], valid in h=1 half

        // ---- broadcast h2(t) once -> carried W_hh2 partial for t+1 ----
        hA2e = 0.0f; hA2o = 0.0f; hB2e = 0.0f; hB2o = 0.0f;
#pragma unroll
        for (int j = 0; j < 30; j += 2) {
            const float s0 = rl(hh2, 32 + j);
            const float s1 = rl(hh2, 33 + j);
            hA2e = fmaf(wh2A[j],     s0, hA2e);
            hA2o = fmaf(wh2A[j + 1], s1, hA2o);
            hB2e = fmaf(wh2B[j],     s0, hB2e);
            hB2o = fmaf(wh2B[j + 1], s1, hB2o);
        }

        // ---------------- fc head ----------------
        const float s = dpp_reduce63(wfck * hh2);
        if (lane == 63) outp[t] = s + bfc;       // store stays in flight

        // ---------------- x chunk rotate ----------------
        if ((t & 63) == 63) {
            xv_cur = xv_nxt;
            if (t + 65 < TSTEPS) xv_nxt = xp[t + 65 + lane];
        }
    }
}

extern "C" void kernel_launch(void* const* d_in, const int* in_sizes, int n_in,
                              void* d_out, int out_size, void* d_ws, size_t ws_size,
                              hipStream_t stream)
{
    const float* x     = (const float*)d_in[0];
    const float* w_ih1 = (const float*)d_in[1];
    const float* w_hh1 = (const float*)d_in[2];
    const float* b_ih1 = (const float*)d_in[3];
    const float* b_hh1 = (const float*)d_in[4];
    const float* w_ih2 = (const float*)d_in[5];
    const float* w_hh2 = (const float*)d_in[6];
    const float* b_ih2 = (const float*)d_in[7];
    const float* b_hh2 = (const float*)d_in[8];
    const float* w_fc  = (const float*)d_in[9];
    const float* b_fc  = (const float*)d_in[10];
    float* out = (float*)d_out;

    lstm2_kernel<<<BATCH, 64, 0, stream>>>(x, w_ih1, w_hh1, b_ih1, b_hh1,
                                           w_ih2, w_hh2, b_ih2, b_hh2,
                                           w_fc, b_fc, out);
}

// Round 2
// 1150.121 us; speedup vs baseline: 1.1223x; 1.1223x over previous
//
#include <hip/hip_runtime.h>

typedef float v2f __attribute__((ext_vector_type(2)));
typedef unsigned long long u64;

#define HID 30
#define TSTEPS 2048
#define BATCH 512
#define L2E 1.4426950408889634f

__device__ __forceinline__ float fexp2(float x) { return __builtin_amdgcn_exp2f(x); }
__device__ __forceinline__ float frcp(float x)  { return __builtin_amdgcn_rcpf(x); }
__device__ __forceinline__ void  pinf(float& v) { asm("" : "+v"(v)); }
__device__ __forceinline__ void  pinf2(v2f& v)  { asm("" : "+v"(v)); }

// broadcast lane l of v to all lanes (v_readlane -> SGPR)
__device__ __forceinline__ float rl(float v, int l) {
    return __int_as_float(__builtin_amdgcn_readlane(__float_as_int(v), l));
}

// packed FMA, src1 = SGPR pair, broadcast LOW 32b of src1 to both halves:
//   acc.x += w.x * s64.lo ; acc.y += w.y * s64.lo
#define PKFMA_LO(acc, w, s64)                                                \
    asm("v_pk_fma_f32 %0, %1, %2, %0 op_sel:[0,0,0] op_sel_hi:[1,0,1]"       \
        : "+v"(acc) : "v"(w), "s"(s64))
// broadcast HIGH 32b of src1 to both halves:
//   acc.x += w.x * s64.hi ; acc.y += w.y * s64.hi
#define PKFMA_HI(acc, w, s64)                                                \
    asm("v_pk_fma_f32 %0, %1, %2, %0 op_sel:[0,1,0] op_sel_hi:[1,1,1]"       \
        : "+v"(acc) : "v"(w), "s"(s64))

// p from the other 32-lane half (lane ^ 32) via gfx950 VALU permlane32_swap.
__device__ __forceinline__ float other_half(float p, int h) {
#if __has_builtin(__builtin_amdgcn_permlane32_swap)
    auto r = __builtin_amdgcn_permlane32_swap(__float_as_uint(p), __float_as_uint(p),
                                              false, false);
    return __uint_as_float(h ? r[0] : r[1]);
#else
    return __shfl_xor(p, 32);
#endif
}

// Wave-wide sum via DPP (VALU pipe). Valid in lane 63.
__device__ __forceinline__ float dpp_reduce63(float x) {
    x += __int_as_float(__builtin_amdgcn_update_dpp(0, __float_as_int(x), 0x111, 0xf, 0xf, true));
    x += __int_as_float(__builtin_amdgcn_update_dpp(0, __float_as_int(x), 0x112, 0xf, 0xf, true));
    x += __int_as_float(__builtin_amdgcn_update_dpp(0, __float_as_int(x), 0x114, 0xf, 0xf, true));
    x += __int_as_float(__builtin_amdgcn_update_dpp(0, __float_as_int(x), 0x118, 0xf, 0xf, true));
    x += __int_as_float(__builtin_amdgcn_update_dpp(0, __float_as_int(x), 0x142, 0xf, 0xf, true));
    x += __int_as_float(__builtin_amdgcn_update_dpp(0, __float_as_int(x), 0x143, 0xf, 0xf, true));
    return x;
}

// ONE WAVE PER BATCH ELEMENT — no barriers, no LDS. All weights in VGPR pairs
// ({rowA,rowB} packed -> v_pk_fma_f32, one issue slot per 2 FMAs). h broadcasts
// via readlane into SGPR pairs, consumed with op_sel lo/hi selection (no v_mov).
// NO unroll-2 this time: R1 showed peak pressure > 256 -> spill storm (VGPR=120).
__global__ __launch_bounds__(64)
__attribute__((amdgpu_waves_per_eu(1, 1)))
void lstm2_kernel(const float* __restrict__ x,
                  const float* __restrict__ w_ih1, const float* __restrict__ w_hh1,
                  const float* __restrict__ b_ih1, const float* __restrict__ b_hh1,
                  const float* __restrict__ w_ih2, const float* __restrict__ w_hh2,
                  const float* __restrict__ b_ih2, const float* __restrict__ b_hh2,
                  const float* __restrict__ w_fc,  const float* __restrict__ b_fc,
                  float* __restrict__ out)
{
    const int b    = blockIdx.x;
    const int lane = threadIdx.x & 63;
    const int k    = lane & 31;
    const int h    = lane >> 5;
    const int kk   = (k < HID) ? k : (HID - 1);  // lanes k=30,31 duplicate unit 29
    const int rowA = h * 30 + kk;                // h0: i-row, h1: f-row
    const int rowB = 60 + h * 30 + kk;           // h0: g-row, h1: o-row

    // ---- per-lane weights as {rowA, rowB} register pairs ----
    v2f w1[30], wi2[30], wh2[30];                // 180 VGPRs total
#pragma unroll
    for (int j = 0; j < 30; ++j) {
        w1[j].x  = w_hh1[rowA * HID + j];  w1[j].y  = w_hh1[rowB * HID + j];
        wi2[j].x = w_ih2[rowA * HID + j];  wi2[j].y = w_ih2[rowB * HID + j];
        wh2[j].x = w_hh2[rowA * HID + j];  wh2[j].y = w_hh2[rowB * HID + j];
    }
    v2f b1AB, b2AB, z2;
    b1AB.x = b_ih1[rowA] + b_hh1[rowA];  b1AB.y = b_ih1[rowB] + b_hh1[rowB];
    b2AB.x = b_ih2[rowA] + b_hh2[rowA];  b2AB.y = b_ih2[rowB] + b_hh2[rowB];
    z2.x = 0.0f; z2.y = 0.0f;
    float wxa = w_ih1[rowA];
    float wxb = w_ih1[rowB];
    float wfck = (h && k < HID) ? w_fc[k] : 0.0f;
#pragma unroll
    for (int j = 0; j < 30; ++j) { pinf2(w1[j]); pinf2(wi2[j]); pinf2(wh2[j]); }
    pinf2(b1AB); pinf2(b2AB);
    pinf(wxa); pinf(wxb); pinf(wfck);
    const float bfc = __int_as_float(__builtin_amdgcn_readfirstlane(__float_as_int(b_fc[0])));

    // gate-y activation constants: h0 -> tanh (g), h1 -> sigmoid (o)
    const float cy = h ? (-L2E) : (-2.0f * L2E);
    const float my = h ? 1.0f : 2.0f;
    const float ay = h ? 0.0f : -1.0f;

    float c1 = 0.0f, c2 = 0.0f;

    // carried packed partials (x = rowA, y = rowB; e/o = even/odd j):
    //   aAB1* = b1 + W_hh1 . h1(t-1)   (computed during step t-1)
    //   hAB2* =      W_hh2 . h2(t-1)
    v2f aAB1e = b1AB, aAB1o = z2;
    v2f hAB2e = z2,   hAB2o = z2;

    const float* xp   = x   + (size_t)b * TSTEPS;
    float*       outp = out + (size_t)b * TSTEPS;

    // x double-buffer: xv_cur covers [t & ~63, +64), xv_nxt the next chunk
    float xv_cur = xp[lane];
    float xv_nxt = xp[64 + lane];

    for (int t = 0; t < TSTEPS; ++t) {
        // ---------------- layer 1, step t ----------------
        const float xt = rl(xv_cur, t & 63);
        v2f pre1 = aAB1e + aAB1o;                 // pk_add: {preA, preB}
        pre1.x = fmaf(xt, wxa, pre1.x);
        pre1.y = fmaf(xt, wxb, pre1.y);
        const float gx1 = frcp(1.0f + fexp2(pre1.x * (-L2E)));           // i / f
        const float gy1 = fmaf(frcp(1.0f + fexp2(pre1.y * cy)), my, ay); // g / o
        const float p1  = gx1 * gy1;
        const float px1 = other_half(p1, h);
        c1 = fmaf(gx1, c1, px1);                  // h=1: f*c1 + i*g
        const float tc1 = fmaf(2.0f, frcp(1.0f + fexp2(c1 * (-2.0f * L2E))), -1.0f);
        const float hh1 = gy1 * tc1;              // h1(t)[kk], valid in h=1 half
        const int   h1i = __float_as_int(hh1);

        // ---- broadcast h1(t): feeds W_hh1 (step t+1) AND W_ih2 (step t) ----
        aAB1e = b1AB; aAB1o = z2;
        v2f iAB2e = b2AB, iAB2o = z2;
#pragma unroll
        for (int j = 0; j < 30; j += 2) {
            const unsigned ra = (unsigned)__builtin_amdgcn_readlane(h1i, 32 + j);
            const unsigned rb = (unsigned)__builtin_amdgcn_readlane(h1i, 33 + j);
            const u64 h64 = ((u64)rb << 32) | (u64)ra;   // {h_j, h_j+1} sgpr pair
            PKFMA_LO(aAB1e, w1[j],      h64);
            PKFMA_HI(aAB1o, w1[j + 1],  h64);
            PKFMA_LO(iAB2e, wi2[j],     h64);
            PKFMA_HI(iAB2o, wi2[j + 1], h64);
        }

        // ---------------- layer 2, step t ----------------
        v2f pre2 = (iAB2e + iAB2o) + (hAB2e + hAB2o);
        const float gx2 = frcp(1.0f + fexp2(pre2.x * (-L2E)));
        const float gy2 = fmaf(frcp(1.0f + fexp2(pre2.y * cy)), my, ay);
        const float p2  = gx2 * gy2;
        const float px2 = other_half(p2, h);
        c2 = fmaf(gx2, c2, px2);
        const float tc2 = fmaf(2.0f, frcp(1.0f + fexp2(c2 * (-2.0f * L2E))), -1.0f);
        const float hh2 = gy2 * tc2;              // h2(t)[kk], valid in h=1 half
        const int   h2i = __float_as_int(hh2);

        // fc head issued BEFORE bcast2 so the dpp chain hides under its FMAs
        const float s = dpp_reduce63(wfck * hh2);

        // ---- broadcast h2(t) -> carried W_hh2 partial for t+1 ----
        hAB2e = z2; hAB2o = z2;
#pragma unroll
        for (int j = 0; j < 30; j += 2) {
            const unsigned ra = (unsigned)__builtin_amdgcn_readlane(h2i, 32 + j);
            const unsigned rb = (unsigned)__builtin_amdgcn_readlane(h2i, 33 + j);
            const u64 h64 = ((u64)rb << 32) | (u64)ra;
            PKFMA_LO(hAB2e, wh2[j],     h64);
            PKFMA_HI(hAB2o, wh2[j + 1], h64);
        }

        if (lane == 63) outp[t] = s + bfc;        // store stays in flight

        // ---------------- x chunk rotate ----------------
        if ((t & 63) == 63) {
            xv_cur = xv_nxt;
            if (t + 65 < TSTEPS) xv_nxt = xp[t + 65 + lane];
        }
    }
}

extern "C" void kernel_launch(void* const* d_in, const int* in_sizes, int n_in,
                              void* d_out, int out_size, void* d_ws, size_t ws_size,
                              hipStream_t stream)
{
    const float* x     = (const float*)d_in[0];
    const float* w_ih1 = (const float*)d_in[1];
    const float* w_hh1 = (const float*)d_in[2];
    const float* b_ih1 = (const float*)d_in[3];
    const float* b_hh1 = (const float*)d_in[4];
    const float* w_ih2 = (const float*)d_in[5];
    const float* w_hh2 = (const float*)d_in[6];
    const float* b_ih2 = (const float*)d_in[7];
    const float* b_hh2 = (const float*)d_in[8];
    const float* w_fc  = (const float*)d_in[9];
    const float* b_fc  = (const float*)d_in[10];
    float* out = (float*)d_out;

    lstm2_kernel<<<BATCH, 64, 0, stream>>>(x, w_ih1, w_hh1, b_ih1, b_hh1,
                                           w_ih2, w_hh2, b_ih2, b_hh2,
                                           w_fc, b_fc, out);
}

// Round 4
// 1106.932 us; speedup vs baseline: 1.1661x; 1.0390x over previous
//
#include <hip/hip_runtime.h>

typedef float v2f __attribute__((ext_vector_type(2)));
typedef unsigned long long u64;

#define HID 30
#define TSTEPS 2048
#define BATCH 512
#define L2E 1.4426950408889634f
#define RSLOT 64    // partial ring depth in steps (32 KB of LDS)
#define CHUNK 16    // flag granularity in steps

__device__ __forceinline__ float fexp2(float x) { return __builtin_amdgcn_exp2f(x); }
__device__ __forceinline__ float frcp(float x)  { return __builtin_amdgcn_rcpf(x); }
__device__ __forceinline__ void  pinf(float& v) { asm("" : "+v"(v)); }
__device__ __forceinline__ void  pinf2(v2f& v)  { asm("" : "+v"(v)); }

// packed FMA, src1 = SGPR pair (compiler-allocated -> compiler inserts any
// required SGPR-hazard waits; R3's hand-rolled readlane asm skipped them and
// silently read stale SGPRs). LO: both halves * s64.lo; HI: both * s64.hi.
#define PKFMA_LO(acc, w, s64)                                                \
    asm("v_pk_fma_f32 %0, %1, %2, %0 op_sel:[0,0,0] op_sel_hi:[1,0,1]"       \
        : "+v"(acc) : "v"(w), "s"(s64))
#define PKFMA_HI(acc, w, s64)                                                \
    asm("v_pk_fma_f32 %0, %1, %2, %0 op_sel:[0,1,0] op_sel_hi:[1,1,1]"       \
        : "+v"(acc) : "v"(w), "s"(s64))

// p from the other 32-lane half (lane ^ 32) via gfx950 VALU permlane32_swap.
__device__ __forceinline__ float other_half(float p, int h) {
#if __has_builtin(__builtin_amdgcn_permlane32_swap)
    auto r = __builtin_amdgcn_permlane32_swap(__float_as_uint(p), __float_as_uint(p),
                                              false, false);
    return __uint_as_float(h ? r[0] : r[1]);
#else
    return __shfl_xor(p, 32);
#endif
}

// Wave-wide sum via DPP (VALU pipe). Valid in lane 63.
__device__ __forceinline__ float dpp_reduce63(float x) {
    x += __int_as_float(__builtin_amdgcn_update_dpp(0, __float_as_int(x), 0x111, 0xf, 0xf, true));
    x += __int_as_float(__builtin_amdgcn_update_dpp(0, __float_as_int(x), 0x112, 0xf, 0xf, true));
    x += __int_as_float(__builtin_amdgcn_update_dpp(0, __float_as_int(x), 0x114, 0xf, 0xf, true));
    x += __int_as_float(__builtin_amdgcn_update_dpp(0, __float_as_int(x), 0x118, 0xf, 0xf, true));
    x += __int_as_float(__builtin_amdgcn_update_dpp(0, __float_as_int(x), 0x142, 0xf, 0xf, true));
    x += __int_as_float(__builtin_amdgcn_update_dpp(0, __float_as_int(x), 0x143, 0xf, 0xf, true));
    return x;
}

// DECOUPLED 2-WAVE PIPELINE, one block per batch element, NO per-step barrier.
//   wave0: layer1 recurrence + (W_ih2*h1 + b2) partial -> 64-step LDS ring
//   wave1: W_hh2*h2 + gates2 + fc head, prefetching partials 1 step ahead
// Flags at 16-step granularity (acquire/release, workgroup scope). Each wave
// holds ~150 VGPRs -- under the R1/R2 allocator cliff. Broadcasts use builtin
// readlane (compiler-managed SGPR hazards; the R3 raw-asm version was buggy).
__global__ __launch_bounds__(128, 1)
__attribute__((amdgpu_waves_per_eu(1, 1)))
void lstm2_kernel(const float* __restrict__ x,
                  const float* __restrict__ w_ih1, const float* __restrict__ w_hh1,
                  const float* __restrict__ b_ih1, const float* __restrict__ b_hh1,
                  const float* __restrict__ w_ih2, const float* __restrict__ w_hh2,
                  const float* __restrict__ b_ih2, const float* __restrict__ b_hh2,
                  const float* __restrict__ w_fc,  const float* __restrict__ b_fc,
                  float* __restrict__ out)
{
    const int b    = blockIdx.x;
    const int tid  = threadIdx.x;
    const int wave = tid >> 6;
    const int lane = tid & 63;
    const int k    = lane & 31;
    const int h    = lane >> 5;
    const int kk   = (k < HID) ? k : (HID - 1);  // lanes k=30,31 duplicate unit 29
    const int rowA = h * 30 + kk;                // h0: i-row, h1: f-row
    const int rowB = 60 + h * 30 + kk;           // h0: g-row, h1: o-row

    __shared__ v2f pbuf[RSLOT][64];   // per-step {preA,preB} partials
    __shared__ int prod, cons;
    if (tid == 0) { prod = -1; cons = -1; }
    __syncthreads();                  // only barrier in the kernel

    // gate-y activation constants: h0 -> tanh (g), h1 -> sigmoid (o)
    const float cy = h ? (-L2E) : (-2.0f * L2E);
    const float my = h ? 1.0f : 2.0f;
    const float ay = h ? 0.0f : -1.0f;

    if (wave == 0) {
        // ================= producer: layer1 + W_ih2 partial =================
        v2f w1[30], wi2[30];
#pragma unroll
        for (int j = 0; j < 30; ++j) {
            w1[j].x  = w_hh1[rowA * HID + j];  w1[j].y  = w_hh1[rowB * HID + j];
            wi2[j].x = w_ih2[rowA * HID + j];  wi2[j].y = w_ih2[rowB * HID + j];
        }
        v2f b1AB, b2AB, z2;
        b1AB.x = b_ih1[rowA] + b_hh1[rowA];  b1AB.y = b_ih1[rowB] + b_hh1[rowB];
        b2AB.x = b_ih2[rowA] + b_hh2[rowA];  b2AB.y = b_ih2[rowB] + b_hh2[rowB];
        z2.x = 0.0f; z2.y = 0.0f;
        float wxa = w_ih1[rowA];
        float wxb = w_ih1[rowB];
#pragma unroll
        for (int j = 0; j < 30; ++j) { pinf2(w1[j]); pinf2(wi2[j]); }
        pinf(wxa); pinf(wxb);

        float c1 = 0.0f;
        v2f aAB1e = b1AB, aAB1o = z2;   // carried b1 + W_hh1 . h1(t-1)
        const float* xp = x + (size_t)b * TSTEPS;
        float xv_cur = xp[lane];
        float xv_nxt = xp[64 + lane];

        for (int t = 0; t < TSTEPS; ++t) {
            if ((t & (CHUNK - 1)) == 0 && t >= RSLOT) {
                // ring back-pressure: about to overwrite steps t-64..t-49
                while (__hip_atomic_load(&cons, __ATOMIC_ACQUIRE,
                                         __HIP_MEMORY_SCOPE_WORKGROUP) < t - (RSLOT - CHUNK + 1))
                    __builtin_amdgcn_s_sleep(1);
            }
            // ---------------- layer 1, step t ----------------
            const float xt = __int_as_float(
                __builtin_amdgcn_readlane(__float_as_int(xv_cur), t & 63));
            v2f pre1 = aAB1e + aAB1o;
            pre1.x = fmaf(xt, wxa, pre1.x);
            pre1.y = fmaf(xt, wxb, pre1.y);
            const float gx1 = frcp(1.0f + fexp2(pre1.x * (-L2E)));           // i / f
            const float gy1 = fmaf(frcp(1.0f + fexp2(pre1.y * cy)), my, ay); // g / o
            const float p1  = gx1 * gy1;
            const float px1 = other_half(p1, h);
            c1 = fmaf(gx1, c1, px1);
            const float tc1 = fmaf(2.0f, frcp(1.0f + fexp2(c1 * (-2.0f * L2E))), -1.0f);
            const float hh1 = gy1 * tc1;          // h1(t)[kk], valid in h=1 half
            const int   h1i = __float_as_int(hh1);

            // ---- broadcast h1(t): W_hh1 (for t+1) AND W_ih2 (for t) ----
            aAB1e = b1AB; aAB1o = z2;
            v2f i2e = b2AB, i2o = z2;
#pragma unroll
            for (int j = 0; j < 30; j += 2) {
                const unsigned ra = (unsigned)__builtin_amdgcn_readlane(h1i, 32 + j);
                const unsigned rb = (unsigned)__builtin_amdgcn_readlane(h1i, 33 + j);
                const u64 h64 = ((u64)rb << 32) | (u64)ra;   // {h_j, h_j+1}
                PKFMA_LO(aAB1e, w1[j],      h64);
                PKFMA_HI(aAB1o, w1[j + 1],  h64);
                PKFMA_LO(i2e,   wi2[j],     h64);
                PKFMA_HI(i2o,   wi2[j + 1], h64);
            }

            pbuf[t & (RSLOT - 1)][lane] = i2e + i2o;   // publish partial(t)
            if ((t & (CHUNK - 1)) == (CHUNK - 1) && lane == 0)
                __hip_atomic_store(&prod, t, __ATOMIC_RELEASE,
                                   __HIP_MEMORY_SCOPE_WORKGROUP);

            if ((t & 63) == 63) {                      // x chunk rotate
                xv_cur = xv_nxt;
                if (t + 65 < TSTEPS) xv_nxt = xp[t + 65 + lane];
            }
        }
    } else {
        // ================= consumer: W_hh2 + gates2 + fc =================
        v2f wh2[30];
#pragma unroll
        for (int j = 0; j < 30; ++j) {
            wh2[j].x = w_hh2[rowA * HID + j];  wh2[j].y = w_hh2[rowB * HID + j];
        }
        v2f z2; z2.x = 0.0f; z2.y = 0.0f;
#pragma unroll
        for (int j = 0; j < 30; ++j) pinf2(wh2[j]);
        float wfck = (h && k < HID) ? w_fc[k] : 0.0f;
        pinf(wfck);
        const float bfc  = __int_as_float(
            __builtin_amdgcn_readfirstlane(__float_as_int(b_fc[0])));
        float c2 = 0.0f;
        v2f hAB2e = z2, hAB2o = z2;     // carried W_hh2 . h2(t-1)
        float* outp = out + (size_t)b * TSTEPS;

        // prologue: wait for chunk 0, prefetch partial(0)
        while (__hip_atomic_load(&prod, __ATOMIC_ACQUIRE,
                                 __HIP_MEMORY_SCOPE_WORKGROUP) < CHUNK - 1)
            __builtin_amdgcn_s_sleep(1);
        v2f part_c = pbuf[0][lane];

        for (int t = 0; t < TSTEPS; ++t) {
            // ---------------- layer 2, step t ----------------
            const v2f pre2 = (hAB2e + hAB2o) + part_c;
            const float gx2 = frcp(1.0f + fexp2(pre2.x * (-L2E)));
            const float gy2 = fmaf(frcp(1.0f + fexp2(pre2.y * cy)), my, ay);
            const float p2  = gx2 * gy2;
            const float px2 = other_half(p2, h);
            c2 = fmaf(gx2, c2, px2);
            const float tc2 = fmaf(2.0f, frcp(1.0f + fexp2(c2 * (-2.0f * L2E))), -1.0f);
            const float hh2 = gy2 * tc2;          // h2(t)[kk], valid in h=1 half
            const int   h2i = __float_as_int(hh2);

            // prefetch partial(t+1) -- hidden under the broadcast loop below
            v2f part_n = part_c;
            if (t + 1 < TSTEPS) {
                const int tn = t + 1;
                if ((tn & (CHUNK - 1)) == 0) {
                    while (__hip_atomic_load(&prod, __ATOMIC_ACQUIRE,
                                             __HIP_MEMORY_SCOPE_WORKGROUP) < tn + CHUNK - 1)
                        __builtin_amdgcn_s_sleep(1);
                }
                part_n = pbuf[tn & (RSLOT - 1)][lane];
            }

            // ---- broadcast h2(t) -> carried W_hh2 partial for t+1 ----
            hAB2e = z2; hAB2o = z2;
#pragma unroll
            for (int j = 0; j < 30; j += 2) {
                const unsigned ra = (unsigned)__builtin_amdgcn_readlane(h2i, 32 + j);
                const unsigned rb = (unsigned)__builtin_amdgcn_readlane(h2i, 33 + j);
                const u64 h64 = ((u64)rb << 32) | (u64)ra;
                PKFMA_LO(hAB2e, wh2[j],     h64);
                PKFMA_HI(hAB2o, wh2[j + 1], h64);
            }

            // ---------------- fc head ----------------
            const float s = dpp_reduce63(wfck * hh2);
            if (lane == 63) outp[t] = s + bfc;     // store stays in flight

            if ((t & (CHUNK - 1)) == (CHUNK - 1) && lane == 0)
                __hip_atomic_store(&cons, t, __ATOMIC_RELEASE,
                                   __HIP_MEMORY_SCOPE_WORKGROUP);
            part_c = part_n;
        }
    }
}

extern "C" void kernel_launch(void* const* d_in, const int* in_sizes, int n_in,
                              void* d_out, int out_size, void* d_ws, size_t ws_size,
                              hipStream_t stream)
{
    const float* x     = (const float*)d_in[0];
    const float* w_ih1 = (const float*)d_in[1];
    const float* w_hh1 = (const float*)d_in[2];
    const float* b_ih1 = (const float*)d_in[3];
    const float* b_hh1 = (const float*)d_in[4];
    const float* w_ih2 = (const float*)d_in[5];
    const float* w_hh2 = (const float*)d_in[6];
    const float* b_ih2 = (const float*)d_in[7];
    const float* b_hh2 = (const float*)d_in[8];
    const float* w_fc  = (const float*)d_in[9];
    const float* b_fc  = (const float*)d_in[10];
    float* out = (float*)d_out;

    lstm2_kernel<<<BATCH, 128, 0, stream>>>(x, w_ih1, w_hh1, b_ih1, b_hh1,
                                            w_ih2, w_hh2, b_ih2, b_hh2,
                                            w_fc, b_fc, out);
}

// Round 5
// 975.435 us; speedup vs baseline: 1.3233x; 1.1348x over previous
//
#include <hip/hip_runtime.h>

typedef float v2f __attribute__((ext_vector_type(2)));
typedef float v4f __attribute__((ext_vector_type(4)));
typedef unsigned long long u64;

#define HID 30
#define TSTEPS 2048
#define BATCH 512
#define L2E 1.4426950408889634f
#define RSLOT 64    // ring depth in steps
#define CHUNK 16    // flag granularity in steps

__device__ __forceinline__ float fexp2(float x) { return __builtin_amdgcn_exp2f(x); }
__device__ __forceinline__ float frcp(float x)  { return __builtin_amdgcn_rcpf(x); }
__device__ __forceinline__ void  pinf(float& v) { asm("" : "+v"(v)); }
__device__ __forceinline__ void  pinf2(v2f& v)  { asm("" : "+v"(v)); }

// packed FMA, src1 = SGPR pair from builtin readlane (compiler-managed hazards).
#define PKFMA_LO(acc, w, s64)                                                \
    asm("v_pk_fma_f32 %0, %1, %2, %0 op_sel:[0,0,0] op_sel_hi:[1,0,1]"       \
        : "+v"(acc) : "v"(w), "s"(s64))
#define PKFMA_HI(acc, w, s64)                                                \
    asm("v_pk_fma_f32 %0, %1, %2, %0 op_sel:[0,1,0] op_sel_hi:[1,1,1]"       \
        : "+v"(acc) : "v"(w), "s"(s64))
// packed FMA, src1 = VGPR pair (uniform h values loaded from LDS).
#define PKFMA_VLO(acc, w, hv)                                                \
    asm("v_pk_fma_f32 %0, %1, %2, %0 op_sel:[0,0,0] op_sel_hi:[1,0,1]"       \
        : "+v"(acc) : "v"(w), "v"(hv))
#define PKFMA_VHI(acc, w, hv)                                                \
    asm("v_pk_fma_f32 %0, %1, %2, %0 op_sel:[0,1,0] op_sel_hi:[1,1,1]"       \
        : "+v"(acc) : "v"(w), "v"(hv))

// p from the other 32-lane half (lane ^ 32) via gfx950 VALU permlane32_swap.
__device__ __forceinline__ float other_half(float p, int h) {
#if __has_builtin(__builtin_amdgcn_permlane32_swap)
    auto r = __builtin_amdgcn_permlane32_swap(__float_as_uint(p), __float_as_uint(p),
                                              false, false);
    return __uint_as_float(h ? r[0] : r[1]);
#else
    return __shfl_xor(p, 32);
#endif
}

// Wave-wide sum via DPP (VALU pipe). Valid in lane 63.
__device__ __forceinline__ float dpp_reduce63(float x) {
    x += __int_as_float(__builtin_amdgcn_update_dpp(0, __float_as_int(x), 0x111, 0xf, 0xf, true));
    x += __int_as_float(__builtin_amdgcn_update_dpp(0, __float_as_int(x), 0x112, 0xf, 0xf, true));
    x += __int_as_float(__builtin_amdgcn_update_dpp(0, __float_as_int(x), 0x114, 0xf, 0xf, true));
    x += __int_as_float(__builtin_amdgcn_update_dpp(0, __float_as_int(x), 0x118, 0xf, 0xf, true));
    x += __int_as_float(__builtin_amdgcn_update_dpp(0, __float_as_int(x), 0x142, 0xf, 0xf, true));
    x += __int_as_float(__builtin_amdgcn_update_dpp(0, __float_as_int(x), 0x143, 0xf, 0xf, true));
    return x;
}

// DECOUPLED 3-WAVE CHAIN, one block per batch element, no per-step barrier.
//   wave0: layer1 recurrence (W_hh1, 60 wregs)     -> h1 ring
//   wave1: W_ih2*h1 + b2 partial (60 wregs)        -> partial ring
//   wave2: W_hh2*h2 + gates2 + fc (60 wregs)
// Every wave's live set ~100 VGPRs: UNDER the empirical ~128 allocator budget
// (R1/R2/R4 all spilled when a wave needed 120+ weight regs; R0's 60-reg waves
// allocated cleanly at 112). Flags at 16-step granularity, R4-proven protocol.
__global__ __launch_bounds__(192, 1)
void lstm2_kernel(const float* __restrict__ x,
                  const float* __restrict__ w_ih1, const float* __restrict__ w_hh1,
                  const float* __restrict__ b_ih1, const float* __restrict__ b_hh1,
                  const float* __restrict__ w_ih2, const float* __restrict__ w_hh2,
                  const float* __restrict__ b_ih2, const float* __restrict__ b_hh2,
                  const float* __restrict__ w_fc,  const float* __restrict__ b_fc,
                  float* __restrict__ out)
{
    const int b    = blockIdx.x;
    const int tid  = threadIdx.x;
    const int wave = tid >> 6;
    const int lane = tid & 63;
    const int k    = lane & 31;
    const int h    = lane >> 5;
    const int kk   = (k < HID) ? k : (HID - 1);  // lanes k=30,31 duplicate unit 29
    const int rowA = h * 30 + kk;                // h0: i-row, h1: f-row
    const int rowB = 60 + h * 30 + kk;           // h0: g-row, h1: o-row

    __shared__ __align__(16) float h1ring[RSLOT][32];  // h1(t) (30 used)
    __shared__ __align__(16) v2f   pring[RSLOT][64];   // {preA,preB} partials
    __shared__ int f01, f12, c10, c21;
    if (tid == 0) { f01 = -1; f12 = -1; c10 = -1; c21 = -1; }
    __syncthreads();                  // only barrier in the kernel

    // gate-y activation constants: h0 -> tanh (g), h1 -> sigmoid (o)
    const float cy = h ? (-L2E) : (-2.0f * L2E);
    const float my = h ? 1.0f : 2.0f;
    const float ay = h ? 0.0f : -1.0f;

    if (wave == 0) {
        // ================= stage 0: layer1 recurrence =================
        v2f w1[30];
#pragma unroll
        for (int j = 0; j < 30; ++j) {
            w1[j].x = w_hh1[rowA * HID + j];  w1[j].y = w_hh1[rowB * HID + j];
        }
        v2f b1AB, z2;
        b1AB.x = b_ih1[rowA] + b_hh1[rowA];  b1AB.y = b_ih1[rowB] + b_hh1[rowB];
        z2.x = 0.0f; z2.y = 0.0f;
        float wxa = w_ih1[rowA];
        float wxb = w_ih1[rowB];
#pragma unroll
        for (int j = 0; j < 30; ++j) pinf2(w1[j]);
        pinf(wxa); pinf(wxb);

        float c1 = 0.0f;
        v2f aABe = b1AB, aABo = z2;     // carried b1 + W_hh1 . h1(t-1)
        const float* xp = x + (size_t)b * TSTEPS;
        float xv_cur = xp[lane];
        float xv_nxt = xp[64 + lane];

        for (int t = 0; t < TSTEPS; ++t) {
            if ((t & (CHUNK - 1)) == 0 && t >= RSLOT) {
                // h1-ring back-pressure
                while (__hip_atomic_load(&c10, __ATOMIC_ACQUIRE,
                                         __HIP_MEMORY_SCOPE_WORKGROUP) < t - (RSLOT - CHUNK + 1))
                    __builtin_amdgcn_s_sleep(1);
            }
            // ---------------- layer 1, step t ----------------
            const float xt = __int_as_float(
                __builtin_amdgcn_readlane(__float_as_int(xv_cur), t & 63));
            v2f pre1 = aABe + aABo;
            pre1.x = fmaf(xt, wxa, pre1.x);
            pre1.y = fmaf(xt, wxb, pre1.y);
            const float gx1 = frcp(1.0f + fexp2(pre1.x * (-L2E)));           // i / f
            const float gy1 = fmaf(frcp(1.0f + fexp2(pre1.y * cy)), my, ay); // g / o
            const float p1  = gx1 * gy1;
            const float px1 = other_half(p1, h);
            c1 = fmaf(gx1, c1, px1);
            const float tc1 = fmaf(2.0f, frcp(1.0f + fexp2(c1 * (-2.0f * L2E))), -1.0f);
            const float hh1 = gy1 * tc1;          // h1(t)[kk], valid in h=1 half
            const int   h1i = __float_as_int(hh1);

            // ---- broadcast h1(t) -> carried W_hh1 partial for t+1 ----
            aABe = b1AB; aABo = z2;
#pragma unroll
            for (int j = 0; j < 30; j += 2) {
                const unsigned ra = (unsigned)__builtin_amdgcn_readlane(h1i, 32 + j);
                const unsigned rb = (unsigned)__builtin_amdgcn_readlane(h1i, 33 + j);
                const u64 h64 = ((u64)rb << 32) | (u64)ra;   // {h_j, h_j+1}
                PKFMA_LO(aABe, w1[j],     h64);
                PKFMA_HI(aABo, w1[j + 1], h64);
            }

            if (h) h1ring[t & (RSLOT - 1)][kk] = hh1;   // publish h1(t)
            if ((t & (CHUNK - 1)) == (CHUNK - 1) && lane == 0)
                __hip_atomic_store(&f01, t, __ATOMIC_RELEASE,
                                   __HIP_MEMORY_SCOPE_WORKGROUP);

            if ((t & 63) == 63) {                       // x chunk rotate
                xv_cur = xv_nxt;
                if (t + 65 < TSTEPS) xv_nxt = xp[t + 65 + lane];
            }
        }
    } else if (wave == 1) {
        // ================= stage 1: W_ih2 * h1 + b2 =================
        v2f wi2[30];
#pragma unroll
        for (int j = 0; j < 30; ++j) {
            wi2[j].x = w_ih2[rowA * HID + j];  wi2[j].y = w_ih2[rowB * HID + j];
        }
        v2f b2AB, z2;
        b2AB.x = b_ih2[rowA] + b_hh2[rowA];  b2AB.y = b_ih2[rowB] + b_hh2[rowB];
        z2.x = 0.0f; z2.y = 0.0f;
#pragma unroll
        for (int j = 0; j < 30; ++j) pinf2(wi2[j]);

        for (int t = 0; t < TSTEPS; ++t) {
            if ((t & (CHUNK - 1)) == 0) {
                if (t >= RSLOT) {   // partial-ring back-pressure
                    while (__hip_atomic_load(&c21, __ATOMIC_ACQUIRE,
                                             __HIP_MEMORY_SCOPE_WORKGROUP) < t - (RSLOT - CHUNK + 1))
                        __builtin_amdgcn_s_sleep(1);
                }
                // h1 availability for this chunk
                while (__hip_atomic_load(&f01, __ATOMIC_ACQUIRE,
                                         __HIP_MEMORY_SCOPE_WORKGROUP) < t + CHUNK - 1)
                    __builtin_amdgcn_s_sleep(1);
            }
            // broadcast-read h1(t) (uniform address -> LDS broadcast, no conflict)
            const v4f* rd = (const v4f*)h1ring[t & (RSLOT - 1)];
            v2f i2e = b2AB, i2o = z2;
#pragma unroll
            for (int c = 0; c < 7; ++c) {
                const v4f hc = rd[c];
                v2f p01, p23;
                p01.x = hc.x; p01.y = hc.y;
                p23.x = hc.z; p23.y = hc.w;
                PKFMA_VLO(i2e, wi2[4 * c + 0], p01);
                PKFMA_VHI(i2o, wi2[4 * c + 1], p01);
                PKFMA_VLO(i2e, wi2[4 * c + 2], p23);
                PKFMA_VHI(i2o, wi2[4 * c + 3], p23);
            }
            const v2f tl = ((const v2f*)h1ring[t & (RSLOT - 1)])[14];  // j=28,29
            PKFMA_VLO(i2e, wi2[28], tl);
            PKFMA_VHI(i2o, wi2[29], tl);

            pring[t & (RSLOT - 1)][lane] = i2e + i2o;   // publish partial(t)
            if ((t & (CHUNK - 1)) == (CHUNK - 1) && lane == 0) {
                __hip_atomic_store(&f12, t, __ATOMIC_RELEASE,
                                   __HIP_MEMORY_SCOPE_WORKGROUP);
                __hip_atomic_store(&c10, t, __ATOMIC_RELEASE,
                                   __HIP_MEMORY_SCOPE_WORKGROUP);
            }
        }
    } else if (wave == 2) {
        // ================= stage 2: W_hh2 + gates2 + fc =================
        v2f wh2[30];
#pragma unroll
        for (int j = 0; j < 30; ++j) {
            wh2[j].x = w_hh2[rowA * HID + j];  wh2[j].y = w_hh2[rowB * HID + j];
        }
        v2f z2; z2.x = 0.0f; z2.y = 0.0f;
#pragma unroll
        for (int j = 0; j < 30; ++j) pinf2(wh2[j]);
        float wfck = (h && k < HID) ? w_fc[k] : 0.0f;
        pinf(wfck);
        const float bfc = __int_as_float(
            __builtin_amdgcn_readfirstlane(__float_as_int(b_fc[0])));
        float c2 = 0.0f;
        v2f hABe = z2, hABo = z2;       // carried W_hh2 . h2(t-1)
        float* outp = out + (size_t)b * TSTEPS;

        // prologue: wait for chunk 0, prefetch partial(0)
        while (__hip_atomic_load(&f12, __ATOMIC_ACQUIRE,
                                 __HIP_MEMORY_SCOPE_WORKGROUP) < CHUNK - 1)
            __builtin_amdgcn_s_sleep(1);
        v2f part_c = pring[0][lane];

        for (int t = 0; t < TSTEPS; ++t) {
            // ---------------- layer 2, step t ----------------
            const v2f pre2 = (hABe + hABo) + part_c;
            const float gx2 = frcp(1.0f + fexp2(pre2.x * (-L2E)));
            const float gy2 = fmaf(frcp(1.0f + fexp2(pre2.y * cy)), my, ay);
            const float p2  = gx2 * gy2;
            const float px2 = other_half(p2, h);
            c2 = fmaf(gx2, c2, px2);
            const float tc2 = fmaf(2.0f, frcp(1.0f + fexp2(c2 * (-2.0f * L2E))), -1.0f);
            const float hh2 = gy2 * tc2;          // h2(t)[kk], valid in h=1 half
            const int   h2i = __float_as_int(hh2);

            // prefetch partial(t+1) -- hidden under the broadcast loop below
            v2f part_n = part_c;
            if (t + 1 < TSTEPS) {
                const int tn = t + 1;
                if ((tn & (CHUNK - 1)) == 0) {
                    while (__hip_atomic_load(&f12, __ATOMIC_ACQUIRE,
                                             __HIP_MEMORY_SCOPE_WORKGROUP) < tn + CHUNK - 1)
                        __builtin_amdgcn_s_sleep(1);
                }
                part_n = pring[tn & (RSLOT - 1)][lane];
            }

            // ---- broadcast h2(t) -> carried W_hh2 partial for t+1 ----
            hABe = z2; hABo = z2;
#pragma unroll
            for (int j = 0; j < 30; j += 2) {
                const unsigned ra = (unsigned)__builtin_amdgcn_readlane(h2i, 32 + j);
                const unsigned rb = (unsigned)__builtin_amdgcn_readlane(h2i, 33 + j);
                const u64 h64 = ((u64)rb << 32) | (u64)ra;
                PKFMA_LO(hABe, wh2[j],     h64);
                PKFMA_HI(hABo, wh2[j + 1], h64);
            }

            // ---------------- fc head ----------------
            const float s = dpp_reduce63(wfck * hh2);
            if (lane == 63) outp[t] = s + bfc;     // store stays in flight

            if ((t & (CHUNK - 1)) == (CHUNK - 1) && lane == 0)
                __hip_atomic_store(&c21, t, __ATOMIC_RELEASE,
                                   __HIP_MEMORY_SCOPE_WORKGROUP);
            part_c = part_n;
        }
    }
}

extern "C" void kernel_launch(void* const* d_in, const int* in_sizes, int n_in,
                              void* d_out, int out_size, void* d_ws, size_t ws_size,
                              hipStream_t stream)
{
    const float* x     = (const float*)d_in[0];
    const float* w_ih1 = (const float*)d_in[1];
    const float* w_hh1 = (const float*)d_in[2];
    const float* b_ih1 = (const float*)d_in[3];
    const float* b_hh1 = (const float*)d_in[4];
    const float* w_ih2 = (const float*)d_in[5];
    const float* w_hh2 = (const float*)d_in[6];
    const float* b_ih2 = (const float*)d_in[7];
    const float* b_hh2 = (const float*)d_in[8];
    const float* w_fc  = (const float*)d_in[9];
    const float* b_fc  = (const float*)d_in[10];
    float* out = (float*)d_out;

    lstm2_kernel<<<BATCH, 192, 0, stream>>>(x, w_ih1, w_hh1, b_ih1, b_hh1,
                                            w_ih2, w_hh2, b_ih2, b_hh2,
                                            w_fc, b_fc, out);
}